// Round 1
// baseline (479.783 us; speedup 1.0000x reference)
//
#include <hip/hip_runtime.h>

#define B_DIM 128
#define T_DIM 512
#define H_DIM 1024
#define O_DIM 256

typedef short bf16x8 __attribute__((ext_vector_type(8)));
typedef float f32x4 __attribute__((ext_vector_type(4)));

__device__ __forceinline__ unsigned short f2bf(float f) {
    union { float f; unsigned u; } v; v.f = f;
    unsigned u = v.u;
    u += 0x7fffu + ((u >> 16) & 1u);   // round-to-nearest-even
    return (unsigned short)(u >> 16);
}
__device__ __forceinline__ unsigned pk2(float a, float b) {
    return (unsigned)f2bf(a) | ((unsigned)f2bf(b) << 16);
}

// ---------------- W transpose + bf16 convert: W[H][O] f32 -> Wt[O][H] bf16 ----
__global__ __launch_bounds__(256) void transpose_w(const float* __restrict__ W,
                                                   unsigned short* __restrict__ Wt) {
    __shared__ float tile[32][33];
    int h0 = blockIdx.x * 32;
    int o0 = blockIdx.y * 32;
    int tx = threadIdx.x;   // 32
    int ty = threadIdx.y;   // 8
#pragma unroll
    for (int j = 0; j < 32; j += 8)
        tile[ty + j][tx] = W[(size_t)(h0 + ty + j) * O_DIM + o0 + tx];
    __syncthreads();
#pragma unroll
    for (int j = 0; j < 32; j += 8)
        Wt[(size_t)(o0 + ty + j) * H_DIM + h0 + tx] = f2bf(tile[tx][ty + j]);
}

// ---------------- GEMM: h2[M=65536][256] = x[M][1024] @ W ---------------------
// 128x128 tile, BK=32, bf16 MFMA 16x16x32, fp32->bf16 convert during A staging.
__global__ __launch_bounds__(256) void gemm_bf16(const float* __restrict__ x,
                                                 const unsigned short* __restrict__ Wt,
                                                 float* __restrict__ h2) {
    __shared__ __align__(16) unsigned short As[128 * 40];  // [128][32+8] pad
    __shared__ __align__(16) unsigned short Bs[128 * 40];

    const int tid  = threadIdx.x;
    const int mb   = blockIdx.x >> 1;
    const int nb   = blockIdx.x & 1;
    const int m0   = mb * 128, n0 = nb * 128;
    const int r    = tid >> 1;       // staging row 0..127
    const int hh   = tid & 1;        // staging half (16 elements of k)
    const int lane = tid & 63;
    const int wave = tid >> 6;
    const int wm   = wave >> 1, wn = wave & 1;   // 2x2 waves, 64x64 each
    const int rowsel = lane & 15, quad = lane >> 4;

    const float* xg = x + (size_t)(m0 + r) * H_DIM + hh * 16;
    const uint4* wg = (const uint4*)(Wt + (size_t)(n0 + r) * H_DIM + hh * 16);
    uint4* awp = (uint4*)&As[r * 40 + hh * 16];
    uint4* bwp = (uint4*)&Bs[r * 40 + hh * 16];

    const unsigned short* afp = &As[(wm * 64 + rowsel) * 40 + quad * 8];
    const unsigned short* bfp = &Bs[(wn * 64 + rowsel) * 40 + quad * 8];

    f32x4 acc[4][4];
#pragma unroll
    for (int i = 0; i < 4; ++i)
#pragma unroll
        for (int j = 0; j < 4; ++j)
            acc[i][j] = (f32x4){0.f, 0.f, 0.f, 0.f};

    for (int k0 = 0; k0 < H_DIM; k0 += 32) {
        const float4* xa = (const float4*)xg;
        float4 a0 = xa[0], a1 = xa[1], a2 = xa[2], a3 = xa[3];
        uint4 wb0 = wg[0], wb1 = wg[1];
        uint4 p0, p1;
        p0.x = pk2(a0.x, a0.y); p0.y = pk2(a0.z, a0.w);
        p0.z = pk2(a1.x, a1.y); p0.w = pk2(a1.z, a1.w);
        p1.x = pk2(a2.x, a2.y); p1.y = pk2(a2.z, a2.w);
        p1.z = pk2(a3.x, a3.y); p1.w = pk2(a3.z, a3.w);
        awp[0] = p0;  awp[1] = p1;
        bwp[0] = wb0; bwp[1] = wb1;
        __syncthreads();

        bf16x8 af[4], bfr[4];
#pragma unroll
        for (int i = 0; i < 4; ++i) {
            af[i]  = *(const bf16x8*)(afp + i * 16 * 40);
            bfr[i] = *(const bf16x8*)(bfp + i * 16 * 40);
        }
#pragma unroll
        for (int i = 0; i < 4; ++i)
#pragma unroll
            for (int j = 0; j < 4; ++j)
                acc[i][j] = __builtin_amdgcn_mfma_f32_16x16x32_bf16(af[i], bfr[j], acc[i][j], 0, 0, 0);
        __syncthreads();

        xg += 32;
        wg += 4;
    }

    // epilogue: C/D layout col=lane&15, row=quad*4+reg
#pragma unroll
    for (int i = 0; i < 4; ++i) {
#pragma unroll
        for (int j = 0; j < 4; ++j) {
            int gm = m0 + wm * 64 + i * 16 + quad * 4;
            int gn = n0 + wn * 64 + j * 16 + rowsel;
            float* cp = h2 + (size_t)gm * O_DIM + gn;
            cp[0 * O_DIM] = acc[i][j][0];
            cp[1 * O_DIM] = acc[i][j][1];
            cp[2 * O_DIM] = acc[i][j][2];
            cp[3 * O_DIM] = acc[i][j][3];
        }
    }
}

// ---------------- chunked leaky-integrate + softmax accumulate ----------------
// alpha^128 = 2.7e-6 -> 128-step warmup makes chunks independent.
__global__ __launch_bounds__(64) void snn_scan(const float* __restrict__ h2,
                                               float* __restrict__ out) {
    const int b = blockIdx.x >> 3;
    const int c = blockIdx.x & 7;
    const int t_start = c * 64;
    const int t_end   = min(t_start + 64, T_DIM - 1);  // 511 steps total
    const int s0      = max(0, t_start - 128);
    const int lane    = threadIdx.x;

    const float A   = 0.90483741803595957f;
    const float OMA = 0.09516258196404043f;

    const float4* p = (const float4*)(h2 + (size_t)b * T_DIM * O_DIM) + (size_t)s0 * 64 + lane;
    float4 mem = {0.f, 0.f, 0.f, 0.f};
    float4 acc = {0.f, 0.f, 0.f, 0.f};
    float4 h = *p;
    for (int t = s0; t < t_end; ++t) {
        p += 64;
        float4 hn = *p;   // prefetch (row t+1 <= 511 always exists)
        mem.x = A * mem.x + OMA * h.x;
        mem.y = A * mem.y + OMA * h.y;
        mem.z = A * mem.z + OMA * h.z;
        mem.w = A * mem.w + OMA * h.w;
        if (t >= t_start) {
            float e0 = __expf(mem.x), e1 = __expf(mem.y);
            float e2 = __expf(mem.z), e3 = __expf(mem.w);
            float s = e0 + e1 + e2 + e3;
            s += __shfl_xor(s, 1);
            s += __shfl_xor(s, 2);
            s += __shfl_xor(s, 4);
            s += __shfl_xor(s, 8);
            s += __shfl_xor(s, 16);
            s += __shfl_xor(s, 32);
            float inv = 1.0f / s;
            acc.x += e0 * inv; acc.y += e1 * inv;
            acc.z += e2 * inv; acc.w += e3 * inv;
        }
        h = hn;
    }
    float* op = out + b * O_DIM + lane * 4;
    atomicAdd(op + 0, acc.x);
    atomicAdd(op + 1, acc.y);
    atomicAdd(op + 2, acc.z);
    atomicAdd(op + 3, acc.w);
}

extern "C" void kernel_launch(void* const* d_in, const int* in_sizes, int n_in,
                              void* d_out, int out_size, void* d_ws, size_t ws_size,
                              hipStream_t stream) {
    const float* x = (const float*)d_in[0];
    const float* W = (const float*)d_in[1];
    float* out = (float*)d_out;

    float* h2 = (float*)d_ws;                                    // 64 MiB
    unsigned short* Wt = (unsigned short*)((char*)d_ws +
                         (size_t)B_DIM * T_DIM * O_DIM * sizeof(float));  // +512 KiB

    hipMemsetAsync(d_out, 0, (size_t)B_DIM * O_DIM * sizeof(float), stream);
    transpose_w<<<dim3(H_DIM / 32, O_DIM / 32), dim3(32, 8), 0, stream>>>(W, Wt);
    gemm_bf16<<<dim3((B_DIM * T_DIM / 128) * 2), 256, 0, stream>>>(x, Wt, h2);
    snn_scan<<<dim3(B_DIM * 8), 64, 0, stream>>>(h2, out);
}

// Round 2
// 464.882 us; speedup vs baseline: 1.0321x; 1.0321x over previous
//
#include <hip/hip_runtime.h>

#define B_DIM 128
#define T_DIM 512
#define H_DIM 1024
#define O_DIM 256

typedef short bf16x8 __attribute__((ext_vector_type(8)));
typedef float f32x4 __attribute__((ext_vector_type(4)));

__device__ __forceinline__ unsigned short f2bf(float f) {
    union { float f; unsigned u; } v; v.f = f;
    unsigned u = v.u;
    u += 0x7fffu + ((u >> 16) & 1u);   // round-to-nearest-even
    return (unsigned short)(u >> 16);
}

// truncating bf16 pack of two floats via one v_perm_b32: D = [hi16(b) : hi16(a)]
__device__ __forceinline__ unsigned tpk(float a, float b) {
    union { float f; unsigned u; } x{a}, y{b};
    return __builtin_amdgcn_perm(y.u, x.u, 0x07060302u);
}

__device__ __forceinline__ void async16(const void* g, void* l) {
    __builtin_amdgcn_global_load_lds(
        (const __attribute__((address_space(1))) unsigned int*)g,
        (__attribute__((address_space(3))) unsigned int*)l, 16, 0, 0);
}

// ---------------- W transpose + bf16 convert: W[H][O] f32 -> Wt[O][H] bf16 ----
__global__ __launch_bounds__(256) void transpose_w(const float* __restrict__ W,
                                                   unsigned short* __restrict__ Wt) {
    __shared__ float tile[32][33];
    int h0 = blockIdx.x * 32;
    int o0 = blockIdx.y * 32;
    int tx = threadIdx.x;   // 32
    int ty = threadIdx.y;   // 8
#pragma unroll
    for (int j = 0; j < 32; j += 8)
        tile[ty + j][tx] = W[(size_t)(h0 + ty + j) * O_DIM + o0 + tx];
    __syncthreads();
#pragma unroll
    for (int j = 0; j < 32; j += 8)
        Wt[(size_t)(o0 + ty + j) * H_DIM + h0 + tx] = f2bf(tile[tx][ty + j]);
}

// ---------------- GEMM: h2[M=65536][256](bf16) = x[M][1024] @ W ---------------
// 128x128 tile, BK=32, bf16 MFMA 16x16x32.
// A: fp32 load + v_perm trunc-pack -> padded As[128][40].
// B: global_load_lds width=16 -> Bs[kq=4][row=128][8] (conflict-free frag reads).
__global__ __launch_bounds__(256) void gemm_bf16(const float* __restrict__ x,
                                                 const unsigned short* __restrict__ Wt,
                                                 unsigned short* __restrict__ h2) {
    __shared__ __align__(16) unsigned short As[128 * 40];   // 10 KiB
    __shared__ __align__(16) unsigned short Bs[4 * 128 * 8]; // 8 KiB

    const int tid  = threadIdx.x;
    const int mb   = blockIdx.x >> 1;
    const int nb   = blockIdx.x & 1;
    const int m0   = mb * 128, n0 = nb * 128;
    const int r    = tid >> 1;       // A staging row 0..127
    const int hh   = tid & 1;        // A staging half (16 k-elements)
    const int lane = tid & 63;
    const int wave = tid >> 6;
    const int wm   = wave >> 1, wn = wave & 1;   // 2x2 waves, 64x64 each
    const int rowsel = lane & 15, quad = lane >> 4;

    const float* xg = x + (size_t)(m0 + r) * H_DIM + hh * 16;
    uint4* awp = (uint4*)&As[r * 40 + hh * 16];

    // B async-copy: wave w covers kq=w, rows {lane, 64+lane}
    const unsigned short* wg0 = Wt + (size_t)(n0 + lane) * H_DIM + wave * 8;
    const unsigned short* wg1 = wg0 + (size_t)64 * H_DIM;
    unsigned short* bs0 = &Bs[wave * 1024];        // + lane*8 implicit (HW)
    unsigned short* bs1 = &Bs[wave * 1024 + 512];

    const unsigned short* afp = &As[(wm * 64 + rowsel) * 40 + quad * 8];
    const unsigned short* bfp = &Bs[quad * 1024 + (wn * 64 + rowsel) * 8];

    f32x4 acc[4][4];
#pragma unroll
    for (int i = 0; i < 4; ++i)
#pragma unroll
        for (int j = 0; j < 4; ++j)
            acc[i][j] = (f32x4){0.f, 0.f, 0.f, 0.f};

    for (int k0 = 0; k0 < H_DIM; k0 += 32) {
        async16(wg0, bs0);
        async16(wg1, bs1);

        const float4* xa = (const float4*)xg;
        float4 a0 = xa[0], a1 = xa[1], a2 = xa[2], a3 = xa[3];
        uint4 p0, p1;
        p0.x = tpk(a0.x, a0.y); p0.y = tpk(a0.z, a0.w);
        p0.z = tpk(a1.x, a1.y); p0.w = tpk(a1.z, a1.w);
        p1.x = tpk(a2.x, a2.y); p1.y = tpk(a2.z, a2.w);
        p1.z = tpk(a3.x, a3.y); p1.w = tpk(a3.z, a3.w);
        awp[0] = p0;  awp[1] = p1;
        __syncthreads();   // drains lgkm + vmcnt (async copies) before use

        bf16x8 af[4], bfr[4];
#pragma unroll
        for (int i = 0; i < 4; ++i) {
            af[i]  = *(const bf16x8*)(afp + i * 16 * 40);
            bfr[i] = *(const bf16x8*)(bfp + i * 16 * 8);
        }
#pragma unroll
        for (int i = 0; i < 4; ++i)
#pragma unroll
            for (int j = 0; j < 4; ++j)
                acc[i][j] = __builtin_amdgcn_mfma_f32_16x16x32_bf16(af[i], bfr[j], acc[i][j], 0, 0, 0);
        __syncthreads();

        xg += 32;
        wg0 += 32;
        wg1 += 32;
    }

    // epilogue: C/D layout col=lane&15, row=quad*4+reg; store bf16
#pragma unroll
    for (int i = 0; i < 4; ++i) {
#pragma unroll
        for (int j = 0; j < 4; ++j) {
            int gm = m0 + wm * 64 + i * 16 + quad * 4;
            int gn = n0 + wn * 64 + j * 16 + rowsel;
            unsigned short* cp = h2 + (size_t)gm * O_DIM + gn;
            cp[0 * O_DIM] = f2bf(acc[i][j][0]);
            cp[1 * O_DIM] = f2bf(acc[i][j][1]);
            cp[2 * O_DIM] = f2bf(acc[i][j][2]);
            cp[3 * O_DIM] = f2bf(acc[i][j][3]);
        }
    }
}

// ---------------- chunked leaky-integrate + softmax accumulate ----------------
// alpha^64 = 1.6e-3 -> 64-step warmup; h2 in bf16; 4-deep prefetch ring.
__global__ __launch_bounds__(64) void snn_scan(const unsigned short* __restrict__ h2,
                                               float* __restrict__ out) {
    const int b = blockIdx.x >> 3;
    const int c = blockIdx.x & 7;
    const int t_start = c * 64;
    const int t_end   = min(t_start + 64, T_DIM - 1);  // 511 steps total
    const int s0      = max(0, t_start - 64);
    const int lane    = threadIdx.x;

    const float A   = 0.90483741803595957f;
    const float OMA = 0.09516258196404043f;

    const unsigned short* base = h2 + (size_t)b * T_DIM * O_DIM + lane * 4;
#define LD(row) (*(const uint2*)(base + (size_t)(row) * O_DIM))

    float4 mem = {0.f, 0.f, 0.f, 0.f};
    float4 acc = {0.f, 0.f, 0.f, 0.f};

    uint2 u0 = LD(s0), u1 = LD(s0 + 1), u2 = LD(s0 + 2), u3 = LD(s0 + 3);

    const int nIter = (t_end - s0 + 3) & ~3;

#define STEP(U, T)                                                              \
    {                                                                           \
        union { unsigned u; float f; } l0, h0, l1, h1;                          \
        l0.u = (U).x << 16; h0.u = (U).x & 0xffff0000u;                         \
        l1.u = (U).y << 16; h1.u = (U).y & 0xffff0000u;                         \
        mem.x = A * mem.x + OMA * l0.f;                                         \
        mem.y = A * mem.y + OMA * h0.f;                                         \
        mem.z = A * mem.z + OMA * l1.f;                                         \
        mem.w = A * mem.w + OMA * h1.f;                                         \
        if ((T) >= t_start && (T) < t_end) {                                    \
            float e0 = __expf(mem.x), e1 = __expf(mem.y);                       \
            float e2 = __expf(mem.z), e3 = __expf(mem.w);                       \
            float s = e0 + e1 + e2 + e3;                                        \
            s += __shfl_xor(s, 1);                                              \
            s += __shfl_xor(s, 2);                                              \
            s += __shfl_xor(s, 4);                                              \
            s += __shfl_xor(s, 8);                                              \
            s += __shfl_xor(s, 16);                                             \
            s += __shfl_xor(s, 32);                                             \
            float inv = 1.0f / s;                                               \
            acc.x += e0 * inv; acc.y += e1 * inv;                               \
            acc.z += e2 * inv; acc.w += e3 * inv;                               \
        }                                                                       \
    }

    for (int t = s0; t < s0 + nIter; t += 4) {
        STEP(u0, t);     u0 = LD(min(t + 4, T_DIM - 1));
        STEP(u1, t + 1); u1 = LD(min(t + 5, T_DIM - 1));
        STEP(u2, t + 2); u2 = LD(min(t + 6, T_DIM - 1));
        STEP(u3, t + 3); u3 = LD(min(t + 7, T_DIM - 1));
    }
#undef STEP
#undef LD

    float* op = out + b * O_DIM + lane * 4;
    atomicAdd(op + 0, acc.x);
    atomicAdd(op + 1, acc.y);
    atomicAdd(op + 2, acc.z);
    atomicAdd(op + 3, acc.w);
}

extern "C" void kernel_launch(void* const* d_in, const int* in_sizes, int n_in,
                              void* d_out, int out_size, void* d_ws, size_t ws_size,
                              hipStream_t stream) {
    const float* x = (const float*)d_in[0];
    const float* W = (const float*)d_in[1];
    float* out = (float*)d_out;

    unsigned short* h2 = (unsigned short*)d_ws;                  // 32 MiB (bf16)
    unsigned short* Wt = (unsigned short*)((char*)d_ws +
                         (size_t)B_DIM * T_DIM * O_DIM * sizeof(unsigned short));

    hipMemsetAsync(d_out, 0, (size_t)B_DIM * O_DIM * sizeof(float), stream);
    transpose_w<<<dim3(H_DIM / 32, O_DIM / 32), dim3(32, 8), 0, stream>>>(W, Wt);
    gemm_bf16<<<dim3((B_DIM * T_DIM / 128) * 2), 256, 0, stream>>>(x, Wt, h2);
    snn_scan<<<dim3(B_DIM * 8), 64, 0, stream>>>(h2, out);
}

// Round 3
// 455.660 us; speedup vs baseline: 1.0529x; 1.0202x over previous
//
#include <hip/hip_runtime.h>

#define B_DIM 128
#define T_DIM 512
#define H_DIM 1024
#define O_DIM 256

typedef short bf16x8 __attribute__((ext_vector_type(8)));
typedef float f32x4 __attribute__((ext_vector_type(4)));

__device__ __forceinline__ unsigned short f2bf(float f) {
    union { float f; unsigned u; } v; v.f = f;
    unsigned u = v.u;
    u += 0x7fffu + ((u >> 16) & 1u);   // round-to-nearest-even
    return (unsigned short)(u >> 16);
}

// truncating bf16 pack of two floats via one v_perm_b32: D = [hi16(b) : hi16(a)]
__device__ __forceinline__ unsigned tpk(float a, float b) {
    union { float f; unsigned u; } x{a}, y{b};
    return __builtin_amdgcn_perm(y.u, x.u, 0x07060302u);
}

__device__ __forceinline__ void async16(const void* g, void* l) {
    __builtin_amdgcn_global_load_lds(
        (const __attribute__((address_space(1))) unsigned int*)g,
        (__attribute__((address_space(3))) unsigned int*)l, 16, 0, 0);
}

// ---------------- W transpose + bf16 convert: W[H][O] f32 -> Wt[O][H] bf16 ----
__global__ __launch_bounds__(256) void transpose_w(const float* __restrict__ W,
                                                   unsigned short* __restrict__ Wt) {
    __shared__ float tile[32][33];
    int h0 = blockIdx.x * 32;
    int o0 = blockIdx.y * 32;
    int tx = threadIdx.x;   // 32
    int ty = threadIdx.y;   // 8
#pragma unroll
    for (int j = 0; j < 32; j += 8)
        tile[ty + j][tx] = W[(size_t)(h0 + ty + j) * O_DIM + o0 + tx];
    __syncthreads();
#pragma unroll
    for (int j = 0; j < 32; j += 8)
        Wt[(size_t)(o0 + ty + j) * H_DIM + h0 + tx] = f2bf(tile[tx][ty + j]);
}

// ---------------- GEMM: h2[M=65536][256](bf16) = x[M][1024] @ W ---------------
// 128x128 tile, BK=32, bf16 MFMA 16x16x32, double-buffered LDS.
// A staging: coalesced — instr i of wave w reads rows w*32+i*8..+8, lanes 0..7
//            cover one full 128-B line per row (8 lines/instr, fully consumed).
// B staging: global_load_lds width=16 into Bs[buf][kq=4][row=128][8].
__global__ __launch_bounds__(256, 4) void gemm_bf16(const float* __restrict__ x,
                                                    const unsigned short* __restrict__ Wt,
                                                    unsigned short* __restrict__ h2) {
    __shared__ __align__(16) unsigned short As[2][128 * 40];    // 20 KiB
    __shared__ __align__(16) unsigned short Bs[2][4 * 128 * 8]; // 16 KiB

    const int tid  = threadIdx.x;
    const int mb   = blockIdx.x >> 1;
    const int nb   = blockIdx.x & 1;
    const int m0   = mb * 128, n0 = nb * 128;
    const int lane = tid & 63;
    const int wave = tid >> 6;
    const int wm   = wave >> 1, wn = wave & 1;   // 2x2 waves, 64x64 each
    const int rowsel = lane & 15, quad = lane >> 4;

    // A coalesced staging coords
    const int arow = wave * 32 + (lane >> 3);   // +i*8
    const int akf  = (lane & 7) * 4;            // float (=bf16 col) offset
    const float* ag = x + (size_t)(m0 + arow) * H_DIM + akf;
    const int aoff = arow * 40 + akf;           // LDS elem offset, +i*8*40

    // B async staging: wave w covers kq=w, rows {lane, 64+lane}
    const unsigned short* wg0 = Wt + (size_t)(n0 + lane) * H_DIM + wave * 8;
    const unsigned short* wg1 = wg0 + (size_t)64 * H_DIM;

    f32x4 acc[4][4];
#pragma unroll
    for (int i = 0; i < 4; ++i)
#pragma unroll
        for (int j = 0; j < 4; ++j)
            acc[i][j] = (f32x4){0.f, 0.f, 0.f, 0.f};

    // ---- prologue: stage k=0 into buf 0 ----
    {
        float4 a[4];
#pragma unroll
        for (int i = 0; i < 4; ++i)
            a[i] = *(const float4*)(ag + (size_t)i * 8 * H_DIM);
        async16(wg0, &Bs[0][wave * 1024]);
        async16(wg1, &Bs[0][wave * 1024 + 512]);
#pragma unroll
        for (int i = 0; i < 4; ++i) {
            uint2 p;
            p.x = tpk(a[i].x, a[i].y);
            p.y = tpk(a[i].z, a[i].w);
            *(uint2*)&As[0][aoff + i * 8 * 40] = p;
        }
    }

    for (int k = 0; k < 32; ++k) {
        const int cur = k & 1, nxt = cur ^ 1;
        __syncthreads();   // buf[cur] committed (writes issued >= 1 iter ago)

        float4 a[4];
        if (k + 1 < 32) {
            const float* agk = ag + (size_t)(k + 1) * 32;
#pragma unroll
            for (int i = 0; i < 4; ++i)
                a[i] = *(const float4*)(agk + (size_t)i * 8 * H_DIM);
            async16(wg0 + (size_t)(k + 1) * 32, &Bs[nxt][wave * 1024]);
            async16(wg1 + (size_t)(k + 1) * 32, &Bs[nxt][wave * 1024 + 512]);
        }

        bf16x8 af[4], bfr[4];
#pragma unroll
        for (int i = 0; i < 4; ++i) {
            af[i]  = *(const bf16x8*)&As[cur][(wm * 64 + rowsel + i * 16) * 40 + quad * 8];
            bfr[i] = *(const bf16x8*)&Bs[cur][quad * 1024 + (wn * 64 + rowsel + i * 16) * 8];
        }
#pragma unroll
        for (int i = 0; i < 4; ++i)
#pragma unroll
            for (int j = 0; j < 4; ++j)
                acc[i][j] = __builtin_amdgcn_mfma_f32_16x16x32_bf16(af[i], bfr[j], acc[i][j], 0, 0, 0);

        if (k + 1 < 32) {
#pragma unroll
            for (int i = 0; i < 4; ++i) {
                uint2 p;
                p.x = tpk(a[i].x, a[i].y);
                p.y = tpk(a[i].z, a[i].w);
                *(uint2*)&As[nxt][aoff + i * 8 * 40] = p;
            }
        }
    }

    // epilogue: C/D layout col=lane&15, row=quad*4+reg; store bf16
#pragma unroll
    for (int i = 0; i < 4; ++i) {
#pragma unroll
        for (int j = 0; j < 4; ++j) {
            int gm = m0 + wm * 64 + i * 16 + quad * 4;
            int gn = n0 + wn * 64 + j * 16 + rowsel;
            unsigned short* cp = h2 + (size_t)gm * O_DIM + gn;
            cp[0 * O_DIM] = f2bf(acc[i][j][0]);
            cp[1 * O_DIM] = f2bf(acc[i][j][1]);
            cp[2 * O_DIM] = f2bf(acc[i][j][2]);
            cp[3 * O_DIM] = f2bf(acc[i][j][3]);
        }
    }
}

// ---------------- chunked leaky-integrate + softmax accumulate ----------------
// alpha^64 = 1.6e-3 -> 64-step warmup; h2 in bf16; 4-deep prefetch ring.
__global__ __launch_bounds__(64) void snn_scan(const unsigned short* __restrict__ h2,
                                               float* __restrict__ out) {
    const int b = blockIdx.x >> 3;
    const int c = blockIdx.x & 7;
    const int t_start = c * 64;
    const int t_end   = min(t_start + 64, T_DIM - 1);  // 511 steps total
    const int s0      = max(0, t_start - 64);
    const int lane    = threadIdx.x;

    const float A   = 0.90483741803595957f;
    const float OMA = 0.09516258196404043f;

    const unsigned short* base = h2 + (size_t)b * T_DIM * O_DIM + lane * 4;
#define LD(row) (*(const uint2*)(base + (size_t)(row) * O_DIM))

    float4 mem = {0.f, 0.f, 0.f, 0.f};
    float4 acc = {0.f, 0.f, 0.f, 0.f};

    uint2 u0 = LD(s0), u1 = LD(s0 + 1), u2 = LD(s0 + 2), u3 = LD(s0 + 3);

    const int nIter = (t_end - s0 + 3) & ~3;

#define STEP(U, T)                                                              \
    {                                                                           \
        union { unsigned u; float f; } l0, h0, l1, h1;                          \
        l0.u = (U).x << 16; h0.u = (U).x & 0xffff0000u;                         \
        l1.u = (U).y << 16; h1.u = (U).y & 0xffff0000u;                         \
        mem.x = A * mem.x + OMA * l0.f;                                         \
        mem.y = A * mem.y + OMA * h0.f;                                         \
        mem.z = A * mem.z + OMA * l1.f;                                         \
        mem.w = A * mem.w + OMA * h1.f;                                         \
        if ((T) >= t_start && (T) < t_end) {                                    \
            float e0 = __expf(mem.x), e1 = __expf(mem.y);                       \
            float e2 = __expf(mem.z), e3 = __expf(mem.w);                       \
            float s = e0 + e1 + e2 + e3;                                        \
            s += __shfl_xor(s, 1);                                              \
            s += __shfl_xor(s, 2);                                              \
            s += __shfl_xor(s, 4);                                              \
            s += __shfl_xor(s, 8);                                              \
            s += __shfl_xor(s, 16);                                             \
            s += __shfl_xor(s, 32);                                             \
            float inv = 1.0f / s;                                               \
            acc.x += e0 * inv; acc.y += e1 * inv;                               \
            acc.z += e2 * inv; acc.w += e3 * inv;                               \
        }                                                                       \
    }

    for (int t = s0; t < s0 + nIter; t += 4) {
        STEP(u0, t);     u0 = LD(min(t + 4, T_DIM - 1));
        STEP(u1, t + 1); u1 = LD(min(t + 5, T_DIM - 1));
        STEP(u2, t + 2); u2 = LD(min(t + 6, T_DIM - 1));
        STEP(u3, t + 3); u3 = LD(min(t + 7, T_DIM - 1));
    }
#undef STEP
#undef LD

    float* op = out + b * O_DIM + lane * 4;
    atomicAdd(op + 0, acc.x);
    atomicAdd(op + 1, acc.y);
    atomicAdd(op + 2, acc.z);
    atomicAdd(op + 3, acc.w);
}

extern "C" void kernel_launch(void* const* d_in, const int* in_sizes, int n_in,
                              void* d_out, int out_size, void* d_ws, size_t ws_size,
                              hipStream_t stream) {
    const float* x = (const float*)d_in[0];
    const float* W = (const float*)d_in[1];
    float* out = (float*)d_out;

    unsigned short* h2 = (unsigned short*)d_ws;                  // 32 MiB (bf16)
    unsigned short* Wt = (unsigned short*)((char*)d_ws +
                         (size_t)B_DIM * T_DIM * O_DIM * sizeof(unsigned short));

    hipMemsetAsync(d_out, 0, (size_t)B_DIM * O_DIM * sizeof(float), stream);
    transpose_w<<<dim3(H_DIM / 32, O_DIM / 32), dim3(32, 8), 0, stream>>>(W, Wt);
    gemm_bf16<<<dim3((B_DIM * T_DIM / 128) * 2), 256, 0, stream>>>(x, Wt, h2);
    snn_scan<<<dim3(B_DIM * 8), 64, 0, stream>>>(h2, out);
}

// Round 4
// 444.488 us; speedup vs baseline: 1.0794x; 1.0251x over previous
//
#include <hip/hip_runtime.h>

#define B_DIM 128
#define T_DIM 512
#define H_DIM 1024
#define O_DIM 256

typedef short bf16x8 __attribute__((ext_vector_type(8)));
typedef float f32x4 __attribute__((ext_vector_type(4)));

__device__ __forceinline__ unsigned short f2bf(float f) {
    union { float f; unsigned u; } v; v.f = f;
    unsigned u = v.u;
    u += 0x7fffu + ((u >> 16) & 1u);   // round-to-nearest-even
    return (unsigned short)(u >> 16);
}

// truncating bf16 pack of two floats via one v_perm_b32: D = [hi16(b) : hi16(a)]
__device__ __forceinline__ unsigned tpk(float a, float b) {
    union { float f; unsigned u; } x{a}, y{b};
    return __builtin_amdgcn_perm(y.u, x.u, 0x07060302u);
}

__device__ __forceinline__ void async16(const void* g, void* l) {
    __builtin_amdgcn_global_load_lds(
        (const __attribute__((address_space(1))) unsigned int*)g,
        (__attribute__((address_space(3))) unsigned int*)l, 16, 0, 0);
}

// ---- W[H][O] f32 -> Wt_tiled bf16, pre-tiled to the GEMM's exact LDS image ----
// Wt_tiled[nb 2][kc 32][kq 4][row 128][8]:  element (o,h) ->
//   (o>>7)*131072 + (h>>5)*4096 + ((h>>3)&3)*1024 + (o&127)*8 + (h&7)
__global__ __launch_bounds__(256) void transpose_w(const float* __restrict__ W,
                                                   unsigned short* __restrict__ Wt) {
    __shared__ float tile[32][33];
    int h0 = blockIdx.x * 32;
    int o0 = blockIdx.y * 32;
    int tx = threadIdx.x;   // 32
    int ty = threadIdx.y;   // 8
#pragma unroll
    for (int j = 0; j < 32; j += 8)
        tile[ty + j][tx] = W[(size_t)(h0 + ty + j) * O_DIM + o0 + tx];
    __syncthreads();
    int h = h0 + tx;
#pragma unroll
    for (int j = 0; j < 32; j += 8) {
        int o = o0 + ty + j;
        size_t idx = (size_t)(o >> 7) * 131072 + (size_t)(h >> 5) * 4096 +
                     (size_t)((h >> 3) & 3) * 1024 + (size_t)(o & 127) * 8 + (h & 7);
        Wt[idx] = f2bf(tile[tx][ty + j]);
    }
}

// ---------------- GEMM: h2[M=65536][256](bf16) = x[M][1024] @ W ---------------
// 128x128 tile, BK=32, bf16 MFMA 16x16x32, double-buffered LDS.
// A: coalesced float4 loads (8 lines/instr, fully consumed) + v_perm trunc-pack.
// B: global_load_lds width=16 from PRE-TILED Wt (global addrs = base + tid*16,
//    fully contiguous -> 8 consecutive lines/instr, no scatter).
__global__ __launch_bounds__(256, 4) void gemm_bf16(const float* __restrict__ x,
                                                    const unsigned short* __restrict__ Wtt,
                                                    unsigned short* __restrict__ h2) {
    __shared__ __align__(16) unsigned short As[2][128 * 40];    // 20 KiB
    __shared__ __align__(16) unsigned short Bs[2][4096];        // 16 KiB

    const int tid  = threadIdx.x;
    const int mb   = blockIdx.x >> 1;
    const int nb   = blockIdx.x & 1;
    const int m0   = mb * 128, n0 = nb * 128;
    const int lane = tid & 63;
    const int wave = tid >> 6;
    const int wm   = wave >> 1, wn = wave & 1;   // 2x2 waves, 64x64 each
    const int rowsel = lane & 15, quad = lane >> 4;

    // A coalesced staging coords: instr i covers rows wave*32+i*8..+8,
    // lanes 0..7 cover one full 128-B line per row.
    const int arow = wave * 32 + (lane >> 3);
    const int akf  = (lane & 7) * 4;
    const float* ag = x + (size_t)(m0 + arow) * H_DIM + akf;
    const int aoff = arow * 40 + akf;

    // B staging from pre-tiled Wt: per k-chunk an 8-KB contiguous image.
    const unsigned short* bg = Wtt + (size_t)nb * 131072 + (size_t)tid * 8;
    unsigned short* bl0 = (unsigned short*)&Bs[0][tid * 8];
    unsigned short* bl1 = (unsigned short*)&Bs[1][tid * 8];

    f32x4 acc[4][4];
#pragma unroll
    for (int i = 0; i < 4; ++i)
#pragma unroll
        for (int j = 0; j < 4; ++j)
            acc[i][j] = (f32x4){0.f, 0.f, 0.f, 0.f};

    // ---- prologue: stage k=0 into buf 0 ----
    {
        float4 a[4];
#pragma unroll
        for (int i = 0; i < 4; ++i)
            a[i] = *(const float4*)(ag + (size_t)i * 8 * H_DIM);
        async16(bg, bl0);
        async16(bg + 2048, bl0 + 2048);
#pragma unroll
        for (int i = 0; i < 4; ++i) {
            uint2 p;
            p.x = tpk(a[i].x, a[i].y);
            p.y = tpk(a[i].z, a[i].w);
            *(uint2*)&As[0][aoff + i * 8 * 40] = p;
        }
    }

    for (int k = 0; k < 32; ++k) {
        const int cur = k & 1, nxt = cur ^ 1;
        __syncthreads();   // buf[cur] committed (vmcnt/lgkm drained here)

        float4 a[4];
        if (k + 1 < 32) {
            const float* agk = ag + (size_t)(k + 1) * 32;
#pragma unroll
            for (int i = 0; i < 4; ++i)
                a[i] = *(const float4*)(agk + (size_t)i * 8 * H_DIM);
            const unsigned short* bgk = bg + (size_t)(k + 1) * 4096;
            unsigned short* bl = nxt ? bl1 : bl0;
            async16(bgk, bl);
            async16(bgk + 2048, bl + 2048);
        }

        bf16x8 af[4], bfr[4];
#pragma unroll
        for (int i = 0; i < 4; ++i) {
            af[i]  = *(const bf16x8*)&As[cur][(wm * 64 + rowsel + i * 16) * 40 + quad * 8];
            bfr[i] = *(const bf16x8*)&Bs[cur][quad * 1024 + (wn * 64 + rowsel + i * 16) * 8];
        }
#pragma unroll
        for (int i = 0; i < 4; ++i)
#pragma unroll
            for (int j = 0; j < 4; ++j)
                acc[i][j] = __builtin_amdgcn_mfma_f32_16x16x32_bf16(af[i], bfr[j], acc[i][j], 0, 0, 0);

        if (k + 1 < 32) {
#pragma unroll
            for (int i = 0; i < 4; ++i) {
                uint2 p;
                p.x = tpk(a[i].x, a[i].y);
                p.y = tpk(a[i].z, a[i].w);
                *(uint2*)&As[nxt][aoff + i * 8 * 40] = p;
            }
        }
    }

    // epilogue: C/D layout col=lane&15, row=quad*4+reg; store bf16
#pragma unroll
    for (int i = 0; i < 4; ++i) {
#pragma unroll
        for (int j = 0; j < 4; ++j) {
            int gm = m0 + wm * 64 + i * 16 + quad * 4;
            int gn = n0 + wn * 64 + j * 16 + rowsel;
            unsigned short* cp = h2 + (size_t)gm * O_DIM + gn;
            cp[0 * O_DIM] = f2bf(acc[i][j][0]);
            cp[1 * O_DIM] = f2bf(acc[i][j][1]);
            cp[2 * O_DIM] = f2bf(acc[i][j][2]);
            cp[3 * O_DIM] = f2bf(acc[i][j][3]);
        }
    }
}

// ---------------- chunked leaky-integrate + softmax accumulate ----------------
// alpha^64 = 1.6e-3 -> 64-step warmup; h2 in bf16; 4-deep prefetch ring.
__global__ __launch_bounds__(64) void snn_scan(const unsigned short* __restrict__ h2,
                                               float* __restrict__ out) {
    const int b = blockIdx.x >> 3;
    const int c = blockIdx.x & 7;
    const int t_start = c * 64;
    const int t_end   = min(t_start + 64, T_DIM - 1);  // 511 steps total
    const int s0      = max(0, t_start - 64);
    const int lane    = threadIdx.x;

    const float A   = 0.90483741803595957f;
    const float OMA = 0.09516258196404043f;

    const unsigned short* base = h2 + (size_t)b * T_DIM * O_DIM + lane * 4;
#define LD(row) (*(const uint2*)(base + (size_t)(row) * O_DIM))

    float4 mem = {0.f, 0.f, 0.f, 0.f};
    float4 acc = {0.f, 0.f, 0.f, 0.f};

    uint2 u0 = LD(s0), u1 = LD(s0 + 1), u2 = LD(s0 + 2), u3 = LD(s0 + 3);

    const int nIter = (t_end - s0 + 3) & ~3;

#define STEP(U, T)                                                              \
    {                                                                           \
        union { unsigned u; float f; } l0, h0, l1, h1;                          \
        l0.u = (U).x << 16; h0.u = (U).x & 0xffff0000u;                         \
        l1.u = (U).y << 16; h1.u = (U).y & 0xffff0000u;                         \
        mem.x = A * mem.x + OMA * l0.f;                                         \
        mem.y = A * mem.y + OMA * h0.f;                                         \
        mem.z = A * mem.z + OMA * l1.f;                                         \
        mem.w = A * mem.w + OMA * h1.f;                                         \
        if ((T) >= t_start && (T) < t_end) {                                    \
            float e0 = __expf(mem.x), e1 = __expf(mem.y);                       \
            float e2 = __expf(mem.z), e3 = __expf(mem.w);                       \
            float s = e0 + e1 + e2 + e3;                                        \
            s += __shfl_xor(s, 1);                                              \
            s += __shfl_xor(s, 2);                                              \
            s += __shfl_xor(s, 4);                                              \
            s += __shfl_xor(s, 8);                                              \
            s += __shfl_xor(s, 16);                                             \
            s += __shfl_xor(s, 32);                                             \
            float inv = 1.0f / s;                                               \
            acc.x += e0 * inv; acc.y += e1 * inv;                               \
            acc.z += e2 * inv; acc.w += e3 * inv;                               \
        }                                                                       \
    }

    for (int t = s0; t < s0 + nIter; t += 4) {
        STEP(u0, t);     u0 = LD(min(t + 4, T_DIM - 1));
        STEP(u1, t + 1); u1 = LD(min(t + 5, T_DIM - 1));
        STEP(u2, t + 2); u2 = LD(min(t + 6, T_DIM - 1));
        STEP(u3, t + 3); u3 = LD(min(t + 7, T_DIM - 1));
    }
#undef STEP
#undef LD

    float* op = out + b * O_DIM + lane * 4;
    atomicAdd(op + 0, acc.x);
    atomicAdd(op + 1, acc.y);
    atomicAdd(op + 2, acc.z);
    atomicAdd(op + 3, acc.w);
}

extern "C" void kernel_launch(void* const* d_in, const int* in_sizes, int n_in,
                              void* d_out, int out_size, void* d_ws, size_t ws_size,
                              hipStream_t stream) {
    const float* x = (const float*)d_in[0];
    const float* W = (const float*)d_in[1];
    float* out = (float*)d_out;

    unsigned short* h2 = (unsigned short*)d_ws;                  // 32 MiB (bf16)
    unsigned short* Wt = (unsigned short*)((char*)d_ws +
                         (size_t)B_DIM * T_DIM * O_DIM * sizeof(unsigned short));

    hipMemsetAsync(d_out, 0, (size_t)B_DIM * O_DIM * sizeof(float), stream);
    transpose_w<<<dim3(H_DIM / 32, O_DIM / 32), dim3(32, 8), 0, stream>>>(W, Wt);
    gemm_bf16<<<dim3((B_DIM * T_DIM / 128) * 2), 256, 0, stream>>>(x, Wt, h2);
    snn_scan<<<dim3(B_DIM * 8), 64, 0, stream>>>(h2, out);
}